// Round 8
// baseline (141.083 us; speedup 1.0000x reference)
//
#include <hip/hip_runtime.h>

#define NB   1024
#define NL   4096
#define TPB  256
#define QSTEP 1024               // steps per block (quarter row)
#define SPT  4                   // steps per thread

// ws float-offsets
#define WS_BASE 256              // per-row: BASE[10], Rs at +10, stride 16
#define WS_PART 16640            // partials: [row*4+q]*12, 12 floats each

typedef float v2f __attribute__((ext_vector_type(2)));

__device__ __forceinline__ float fast_rcp(float x) { return __builtin_amdgcn_rcpf(x); }
__device__ __forceinline__ float fexp2(float x) { return __builtin_amdgcn_exp2f(x); }  // 2^x
__device__ __forceinline__ float flog2(float x) { return __builtin_amdgcn_logf(x); }   // log2(x)

#define L2E 1.44269504088896340736f
#define LN2 0.69314718055994530942f

// Even part of softplus in log2 domain: F(x) = log2(1+2^x) - x/2 = F(-x).
// Cubic in s=x^2, interpolated at x={0,1.51,3,4}; max |err| ~1e-3 on |x|<=4.
#define SP_C0 1.0f
#define SP_C1 0.0864667f
#define SP_C2 (-0.0015685f)
#define SP_C3 2.5763e-5f

// ---------------- kernel A: weight prep ----------------
__global__ void __launch_bounds__(256) onenet_prep(
    const float* __restrict__ X,   const float* __restrict__ SC,
    const float* __restrict__ pW1, const float* __restrict__ pb1,
    const float* __restrict__ pW2, const float* __restrict__ pb2,
    const float* __restrict__ rW1, const float* __restrict__ rb1,
    const float* __restrict__ rW2, const float* __restrict__ rb2,
    float* __restrict__ ws)
{
    const int gid = blockIdx.x * 256 + threadIdx.x;
    if (gid < NB) {
        float sc0 = SC[gid * 3 + 0], sc1 = SC[gid * 3 + 1], sc2 = SC[gid * 3 + 2];
        float* bp = ws + WS_BASE + gid * 16;
#pragma unroll
        for (int j = 0; j < 10; ++j) {
            float base = fmaf(sc0, pW1[20 + j],
                         fmaf(sc1, pW1[30 + j],
                         fmaf(sc2, pW1[40 + j], pb1[j])));
            bp[j] = L2E * base;
        }
        // r-net on x[:,0,:] = [SOC0, T0, sc0, sc1, sc2] (one-off: exact trans ok)
        const float* x0 = X + (size_t)gid * NL * 5;
        float T0 = x0[2], SOC0 = x0[4];
        float u = rb1[0];
        u = fmaf(SOC0, rW1[0], u);
        u = fmaf(T0,   rW1[1], u);
        u = fmaf(sc0,  rW1[2], u);
        u = fmaf(sc1,  rW1[3], u);
        u = fmaf(sc2,  rW1[4], u);
        float sp = LN2 * flog2(1.0f + fexp2(L2E * u));
        float r  = fmaf(sp, rW2[0], rb2[0]);
        bp[10] = sc2 * (1.0f + r);   // Rs
    }
    // global prescaled weights -> ws[0..74]
    if (blockIdx.x == 0 && threadIdx.x < 75) {
        const int t = threadIdx.x;
        const float LBv[5]   = {0.005f, 0.025f, 0.1f, 0.0f, 0.002f};
        const float UBLB[5]  = {0.015f, 0.045f, 0.9f, 0.055f, 0.023f};
        float v;
        if (t < 20) {
            v = L2E * pW1[t];                       // W1S rows 0..9, W1T rows 10..19
        } else if (t < 70) {
            int k = (t - 20) % 5;
            v = LN2 * 0.0025f * UBLB[k] * pW2[t - 20];   // V[j,k]
        } else {
            int k = t - 70;
            v = LBv[k] + UBLB[k] * fmaf(0.0025f, pb2[k], 0.5f);  // alpha_k
        }
        ws[t] = v;
    }
}

// ---------------- kernel B: main scan-as-reduction ----------------
// block = row*4 + q ; 256 threads x 4 steps = 1024 steps per block.
// Affine (U,S) composition, two systems packed as float2 (.x = U_H, .y = U_1):
//   T_l: U' = a*U + b ; S' = S + (1/I_l)*U  (S-accum uses PRE-step U)
//   theta_k = alpha_k + sum_j softplus2(pre_j) * V[j,k]  (sigmoid linearized)
// softplus2 via even-polynomial (no transcendentals in the hot loop).
// Global step 4095 gets dt = 0 -> identity transition automatically.
__global__ void __launch_bounds__(TPB) onenet_main(
    const float* __restrict__ X, float* __restrict__ ws)
{
    const int bid  = blockIdx.x;
    const int row  = bid >> 2;
    const int q    = bid & 3;
    const int tid  = threadIdx.x;
    const int lane = tid & 63;
    const int w    = tid >> 6;

    // uniform weights (wave-uniform -> scalar loads)
    float W1S[10], W1T[10], BASE[10], V4[10];
    v2f V01[10], V23[10], AL01, AL23;
    float AL4;
#pragma unroll
    for (int j = 0; j < 10; ++j) W1S[j] = ws[j];
#pragma unroll
    for (int j = 0; j < 10; ++j) W1T[j] = ws[10 + j];
#pragma unroll
    for (int j = 0; j < 10; ++j) {
        V01[j].x = ws[20 + 5 * j + 0];
        V01[j].y = ws[20 + 5 * j + 1];
        V23[j].x = ws[20 + 5 * j + 2];
        V23[j].y = ws[20 + 5 * j + 3];
        V4[j]    = ws[20 + 5 * j + 4];
    }
    AL01.x = ws[70]; AL01.y = ws[71];
    AL23.x = ws[72]; AL23.y = ws[73];
    AL4    = ws[74];
    {
        const float* bp = ws + WS_BASE + row * 16;
#pragma unroll
        for (int j = 0; j < 10; ++j) BASE[j] = bp[j];
    }

    const float* xp = X + ((size_t)row * NL + (size_t)(q * QSTEP + tid * SPT)) * 5;

    float f[20];
#pragma unroll
    for (int k = 0; k < 5; ++k)
        *(float4*)&f[4 * k] = reinterpret_cast<const float4*>(xp)[k];
    // t of the step after this thread's last. For the global last step (q==3,
    // tid==255) use its own t -> dt=0 -> identity (also avoids OOB at row 1023).
    float tn = (q == 3 && tid == TPB - 1) ? f[15] : xp[20];

    v2f a = {1.f, 1.f}, b = {0.f, 0.f}, cS = {0.f, 0.f}, dS = {0.f, 0.f};
    float oacc = 0.f, OCV0 = 0.f, I0 = 0.f;

#pragma unroll
    for (int i = 0; i < SPT; ++i) {
        float tt = f[5 * i + 0];
        float Ii = f[5 * i + 1];
        float Tt = f[5 * i + 2];
        float SS = f[5 * i + 4];
        float tnx = (i < SPT - 1) ? f[5 * i + 5] : tn;
        float dt  = tnx - tt;
        float inv = fast_rcp(Ii);

        v2f t01 = AL01, t23 = AL23;
        float t4 = AL4;
#pragma unroll
        for (int j = 0; j < 10; ++j) {
            float pre = fmaf(SS, W1S[j], fmaf(Tt, W1T[j], BASE[j]));
            float s   = pre * pre;
            float p   = fmaf(s, SP_C3, SP_C2);
            p = fmaf(s, p, SP_C1);
            p = fmaf(s, p, SP_C0);
            float lam = fmaf(pre, 0.5f, p);    // softplus2(pre), poly approx
            v2f lam2 = {lam, lam};
            t01 = lam2 * V01[j] + t01;
            t23 = lam2 * V23[j] + t23;
            t4  = fmaf(lam, V4[j], t4);
        }
        // t01.x=R_1, t01.y=RC_r, t23.x=OCV_U, t23.y=M_Hn, t4=K_H
        oacc = fmaf(-t23.x, inv, oacc);
        if (i == 0) { OCV0 = t23.x; I0 = Ii; }

        float g  = dt * t4 * Ii;
        float hh = dt * t01.y;
        v2f sv = {1.f + g, 1.f - hh};
        v2f bv = {g * t23.y, hh * t01.x * Ii};
        v2f iv = {inv, inv};
        cS = iv * a + cS;        // S-accum with pre-step U
        dS = iv * b + dS;
        b  = sv * b + bv;        // then apply T_l
        a  = sv * a;
    }

    // wave-level order-preserving tree reduce (L=self, R=lane+off)
#pragma unroll
    for (int off = 1; off < 64; off <<= 1) {
        v2f a2, b2, c2, d2;
        a2.x = __shfl_down(a.x, off);  a2.y = __shfl_down(a.y, off);
        b2.x = __shfl_down(b.x, off);  b2.y = __shfl_down(b.y, off);
        c2.x = __shfl_down(cS.x, off); c2.y = __shfl_down(cS.y, off);
        d2.x = __shfl_down(dS.x, off); d2.y = __shfl_down(dS.y, off);
        float o2 = __shfl_down(oacc, off);
        v2f nb = a2 * b + b2;
        v2f nc = c2 * a + cS;
        v2f nd = (dS + d2) + c2 * b;
        a = a2 * a; b = nb; cS = nc; dS = nd;
        oacc += o2;
    }

    __shared__ float red[TPB / 64][9];
    if (lane == 0) {
        red[w][0] = a.x;  red[w][1] = a.y;
        red[w][2] = b.x;  red[w][3] = b.y;
        red[w][4] = cS.x; red[w][5] = cS.y;
        red[w][6] = dS.x; red[w][7] = dS.y;
        red[w][8] = oacc;
    }
    __syncthreads();

    if (tid == 0) {
#pragma unroll
        for (int k = 1; k < TPB / 64; ++k) {
            v2f ak, bk, ck, dk;
            ak.x = red[k][0]; ak.y = red[k][1];
            bk.x = red[k][2]; bk.y = red[k][3];
            ck.x = red[k][4]; ck.y = red[k][5];
            dk.x = red[k][6]; dk.y = red[k][7];
            v2f nb = ak * b + bk;
            v2f nc = ck * a + cS;
            v2f nd = (dS + dk) + ck * b;
            a = ak * a; b = nb; cS = nc; dS = nd;
            oacc += red[k][8];
        }
        float* pw = ws + WS_PART + (size_t)bid * 12;
        pw[0] = a.x;  pw[1] = b.x;  pw[2] = cS.x; pw[3] = dS.x;
        pw[4] = a.y;  pw[5] = b.y;  pw[6] = cS.y; pw[7] = dS.y;
        pw[8] = oacc;
        if (q == 0) { pw[9] = OCV0; pw[10] = I0; }
    }
}

// ---------------- kernel C: combine quarters + output ----------------
__global__ void __launch_bounds__(256) onenet_final(
    const float* __restrict__ ws, float* __restrict__ out)
{
    const int row = blockIdx.x * 256 + threadIdx.x;
    if (row >= NB) return;
    const float* p0 = ws + WS_PART + (size_t)row * 48;

    v2f a, b, cS, dS;
    a.x  = p0[0]; a.y  = p0[4];
    b.x  = p0[1]; b.y  = p0[5];
    cS.x = p0[2]; cS.y = p0[6];
    dS.x = p0[3]; dS.y = p0[7];
    float O = p0[8];
    float OCV0 = p0[9], I0 = p0[10];
#pragma unroll
    for (int k = 1; k < 4; ++k) {
        const float* pk = p0 + k * 12;
        v2f ak, bk, ck, dk;
        ak.x = pk[0]; ak.y = pk[4];
        bk.x = pk[1]; bk.y = pk[5];
        ck.x = pk[2]; ck.y = pk[6];
        dk.x = pk[3]; dk.y = pk[7];
        v2f nb = ak * b + bk;
        v2f nc = ck * a + cS;
        v2f nd = (dS + dk) + ck * b;
        a = ak * a; b = nb; cS = nc; dS = nd;
        O += pk[8];
    }
    float Rs  = ws[WS_BASE + row * 16 + 10];
    float U10 = -OCV0 - I0 * Rs;                 // U_H0 = 0
    float SH  = dS.x;                            // sum U_H/I
    float S1  = fmaf(cS.y, U10, dS.y);           // sum U_1/I
    out[row] = (O - SH - S1) * (1.0f / 4096.0f);
}

extern "C" void kernel_launch(void* const* d_in, const int* in_sizes, int n_in,
                              void* d_out, int out_size, void* d_ws, size_t ws_size,
                              hipStream_t stream) {
    const float* X   = (const float*)d_in[0];
    const float* SC  = (const float*)d_in[1];
    const float* pW1 = (const float*)d_in[2];
    const float* pb1 = (const float*)d_in[3];
    const float* pW2 = (const float*)d_in[4];
    const float* pb2 = (const float*)d_in[5];
    const float* rW1 = (const float*)d_in[6];
    const float* rb1 = (const float*)d_in[7];
    const float* rW2 = (const float*)d_in[8];
    const float* rb2 = (const float*)d_in[9];
    float* out = (float*)d_out;
    float* ws  = (float*)d_ws;

    onenet_prep<<<NB / 256, 256, 0, stream>>>(X, SC, pW1, pb1, pW2, pb2,
                                              rW1, rb1, rW2, rb2, ws);
    onenet_main<<<NB * 4, TPB, 0, stream>>>(X, ws);
    onenet_final<<<NB / 256, 256, 0, stream>>>(ws, out);
}

// Round 9
// 138.803 us; speedup vs baseline: 1.0164x; 1.0164x over previous
//
#include <hip/hip_runtime.h>

#define NB   1024
#define NL   4096
#define TPB  256
#define QSTEP 1024               // steps per block (quarter row)
#define SPT  4                   // steps per thread

// ws float-offsets
#define WS_BASE 256              // per-row: BASE[10], Rs at +10, stride 16
#define WS_PART 16640            // partials: [row*4+q]*12, 12 floats each

typedef float v2f __attribute__((ext_vector_type(2)));

__device__ __forceinline__ float fast_rcp(float x) { return __builtin_amdgcn_rcpf(x); }
__device__ __forceinline__ float fexp2(float x) { return __builtin_amdgcn_exp2f(x); }  // 2^x
__device__ __forceinline__ float flog2(float x) { return __builtin_amdgcn_logf(x); }   // log2(x)

#define L2E 1.44269504088896340736f
#define LN2 0.69314718055994530942f

// Even part of softplus in log2 domain: F(x) = log2(1+2^x) - x/2 = F(-x).
// Cubic in s=x^2; max |err| ~1e-3 on |x|<=4.
#define SP_C0 1.0f
#define SP_C1 0.0864667f
#define SP_C2 (-0.0015685f)
#define SP_C3 2.5763e-5f

// ---------------- kernel A: weight prep ----------------
__global__ void __launch_bounds__(256) onenet_prep(
    const float* __restrict__ X,   const float* __restrict__ SC,
    const float* __restrict__ pW1, const float* __restrict__ pb1,
    const float* __restrict__ pW2, const float* __restrict__ pb2,
    const float* __restrict__ rW1, const float* __restrict__ rb1,
    const float* __restrict__ rW2, const float* __restrict__ rb2,
    float* __restrict__ ws)
{
    const int gid = blockIdx.x * 256 + threadIdx.x;
    if (gid < NB) {
        float sc0 = SC[gid * 3 + 0], sc1 = SC[gid * 3 + 1], sc2 = SC[gid * 3 + 2];
        float* bp = ws + WS_BASE + gid * 16;
#pragma unroll
        for (int j = 0; j < 10; ++j) {
            float base = fmaf(sc0, pW1[20 + j],
                         fmaf(sc1, pW1[30 + j],
                         fmaf(sc2, pW1[40 + j], pb1[j])));
            bp[j] = L2E * base;
        }
        // r-net on x[:,0,:] = [SOC0, T0, sc0, sc1, sc2] (one-off: exact trans ok)
        const float* x0 = X + (size_t)gid * NL * 5;
        float T0 = x0[2], SOC0 = x0[4];
        float u = rb1[0];
        u = fmaf(SOC0, rW1[0], u);
        u = fmaf(T0,   rW1[1], u);
        u = fmaf(sc0,  rW1[2], u);
        u = fmaf(sc1,  rW1[3], u);
        u = fmaf(sc2,  rW1[4], u);
        float sp = LN2 * flog2(1.0f + fexp2(L2E * u));
        float r  = fmaf(sp, rW2[0], rb2[0]);
        bp[10] = sc2 * (1.0f + r);   // Rs
    }
    // global prescaled weights -> ws[0..74]
    if (blockIdx.x == 0 && threadIdx.x < 75) {
        const int t = threadIdx.x;
        const float LBv[5]   = {0.005f, 0.025f, 0.1f, 0.0f, 0.002f};
        const float UBLB[5]  = {0.015f, 0.045f, 0.9f, 0.055f, 0.023f};
        float v;
        if (t < 20) {
            v = L2E * pW1[t];                       // W1S rows 0..9, W1T rows 10..19
        } else if (t < 70) {
            int k = (t - 20) % 5;
            v = LN2 * 0.0025f * UBLB[k] * pW2[t - 20];   // V[j,k]
        } else {
            int k = t - 70;
            v = LBv[k] + UBLB[k] * fmaf(0.0025f, pb2[k], 0.5f);  // alpha_k
        }
        ws[t] = v;
    }
}

// ---------------- kernel B: main scan-as-reduction ----------------
// block = row*4 + q ; 256 threads x 4 steps = 1024 steps per block.
// Coalesced global->LDS staging with XOR bank swizzle (float4 index
// w -> w ^ ((w>>3)&7)): writes 2-way/free, strided reads conflict-free.
// Then per-thread affine (U,S) composition as in R7/R8; poly softplus;
// global step 4095 gets dt=0 -> identity automatically.
__global__ void __launch_bounds__(TPB) onenet_main(
    const float* __restrict__ X, float* __restrict__ ws)
{
    __shared__ float4 tile[TPB * 5];          // 20 KB staging
    __shared__ float  red[TPB / 64][9];

    const int bid  = blockIdx.x;
    const int row  = bid >> 2;
    const int q    = bid & 3;
    const int tid  = threadIdx.x;
    const int lane = tid & 63;
    const int w    = tid >> 6;

    // ---- coalesced staging: quarter-row (1024 steps, 20 KB) ----
    const float* Xq = X + ((size_t)row * NL + (size_t)q * QSTEP) * 5;
    {
        const float4* gq = (const float4*)Xq;
#pragma unroll
        for (int k = 0; k < 5; ++k) {
            int widx = tid + TPB * k;
            int sw   = widx ^ ((widx >> 3) & 7);
            tile[sw] = gq[widx];
        }
    }

    // uniform weights (wave-uniform -> scalar loads) while staging in flight
    float W1S[10], W1T[10], BASE[10], V4[10];
    v2f V01[10], V23[10], AL01, AL23;
    float AL4;
#pragma unroll
    for (int j = 0; j < 10; ++j) W1S[j] = ws[j];
#pragma unroll
    for (int j = 0; j < 10; ++j) W1T[j] = ws[10 + j];
#pragma unroll
    for (int j = 0; j < 10; ++j) {
        V01[j].x = ws[20 + 5 * j + 0];
        V01[j].y = ws[20 + 5 * j + 1];
        V23[j].x = ws[20 + 5 * j + 2];
        V23[j].y = ws[20 + 5 * j + 3];
        V4[j]    = ws[20 + 5 * j + 4];
    }
    AL01.x = ws[70]; AL01.y = ws[71];
    AL23.x = ws[72]; AL23.y = ws[73];
    AL4    = ws[74];
    {
        const float* bp = ws + WS_BASE + row * 16;
#pragma unroll
        for (int j = 0; j < 10; ++j) BASE[j] = bp[j];
    }

    __syncthreads();                          // staging visible

    // ---- conflict-free LDS reads: this thread's 4 steps (20 floats) ----
    float f[20];
#pragma unroll
    for (int j = 0; j < 5; ++j) {
        int widx = 5 * tid + j;
        int sw   = widx ^ ((widx >> 3) & 7);
        *(float4*)&f[4 * j] = tile[sw];
    }
    // t of the step after this thread's last
    float tn;
    {
        int wn  = 5 * ((tid + 1) & (TPB - 1));   // clamped for tid==255
        int swn = wn ^ ((wn >> 3) & 7);
        float tl = tile[swn].x;
        if (tid < TPB - 1)      tn = tl;
        else if (q == 3)        tn = f[15];      // dt=0 -> identity at step 4095
        else                    tn = Xq[QSTEP * 5];
    }

    v2f a = {1.f, 1.f}, b = {0.f, 0.f}, cS = {0.f, 0.f}, dS = {0.f, 0.f};
    float oacc = 0.f, OCV0 = 0.f, I0 = 0.f;

#pragma unroll
    for (int i = 0; i < SPT; ++i) {
        float tt = f[5 * i + 0];
        float Ii = f[5 * i + 1];
        float Tt = f[5 * i + 2];
        float SS = f[5 * i + 4];
        float tnx = (i < SPT - 1) ? f[5 * i + 5] : tn;
        float dt  = tnx - tt;
        float inv = fast_rcp(Ii);

        v2f t01 = AL01, t23 = AL23;
        float t4 = AL4;
#pragma unroll
        for (int j = 0; j < 10; ++j) {
            float pre = fmaf(SS, W1S[j], fmaf(Tt, W1T[j], BASE[j]));
            float s   = pre * pre;
            float p   = fmaf(s, SP_C3, SP_C2);
            p = fmaf(s, p, SP_C1);
            p = fmaf(s, p, SP_C0);
            float lam = fmaf(pre, 0.5f, p);    // softplus2(pre), poly approx
            v2f lam2 = {lam, lam};
            t01 = lam2 * V01[j] + t01;
            t23 = lam2 * V23[j] + t23;
            t4  = fmaf(lam, V4[j], t4);
        }
        // t01.x=R_1, t01.y=RC_r, t23.x=OCV_U, t23.y=M_Hn, t4=K_H
        oacc = fmaf(-t23.x, inv, oacc);
        if (i == 0) { OCV0 = t23.x; I0 = Ii; }

        float g  = dt * t4 * Ii;
        float hh = dt * t01.y;
        v2f sv = {1.f + g, 1.f - hh};
        v2f bv = {g * t23.y, hh * t01.x * Ii};
        v2f iv = {inv, inv};
        cS = iv * a + cS;        // S-accum with pre-step U
        dS = iv * b + dS;
        b  = sv * b + bv;        // then apply T_l
        a  = sv * a;
    }

    // wave-level order-preserving tree reduce (L=self, R=lane+off)
#pragma unroll
    for (int off = 1; off < 64; off <<= 1) {
        v2f a2, b2, c2, d2;
        a2.x = __shfl_down(a.x, off);  a2.y = __shfl_down(a.y, off);
        b2.x = __shfl_down(b.x, off);  b2.y = __shfl_down(b.y, off);
        c2.x = __shfl_down(cS.x, off); c2.y = __shfl_down(cS.y, off);
        d2.x = __shfl_down(dS.x, off); d2.y = __shfl_down(dS.y, off);
        float o2 = __shfl_down(oacc, off);
        v2f nb = a2 * b + b2;
        v2f nc = c2 * a + cS;
        v2f nd = (dS + d2) + c2 * b;
        a = a2 * a; b = nb; cS = nc; dS = nd;
        oacc += o2;
    }

    if (lane == 0) {
        red[w][0] = a.x;  red[w][1] = a.y;
        red[w][2] = b.x;  red[w][3] = b.y;
        red[w][4] = cS.x; red[w][5] = cS.y;
        red[w][6] = dS.x; red[w][7] = dS.y;
        red[w][8] = oacc;
    }
    __syncthreads();

    if (tid == 0) {
#pragma unroll
        for (int k = 1; k < TPB / 64; ++k) {
            v2f ak, bk, ck, dk;
            ak.x = red[k][0]; ak.y = red[k][1];
            bk.x = red[k][2]; bk.y = red[k][3];
            ck.x = red[k][4]; ck.y = red[k][5];
            dk.x = red[k][6]; dk.y = red[k][7];
            v2f nb = ak * b + bk;
            v2f nc = ck * a + cS;
            v2f nd = (dS + dk) + ck * b;
            a = ak * a; b = nb; cS = nc; dS = nd;
            oacc += red[k][8];
        }
        float* pw = ws + WS_PART + (size_t)bid * 12;
        pw[0] = a.x;  pw[1] = b.x;  pw[2] = cS.x; pw[3] = dS.x;
        pw[4] = a.y;  pw[5] = b.y;  pw[6] = cS.y; pw[7] = dS.y;
        pw[8] = oacc;
        if (q == 0) { pw[9] = OCV0; pw[10] = I0; }
    }
}

// ---------------- kernel C: combine quarters + output ----------------
__global__ void __launch_bounds__(256) onenet_final(
    const float* __restrict__ ws, float* __restrict__ out)
{
    const int row = blockIdx.x * 256 + threadIdx.x;
    if (row >= NB) return;
    const float* p0 = ws + WS_PART + (size_t)row * 48;

    v2f a, b, cS, dS;
    a.x  = p0[0]; a.y  = p0[4];
    b.x  = p0[1]; b.y  = p0[5];
    cS.x = p0[2]; cS.y = p0[6];
    dS.x = p0[3]; dS.y = p0[7];
    float O = p0[8];
    float OCV0 = p0[9], I0 = p0[10];
#pragma unroll
    for (int k = 1; k < 4; ++k) {
        const float* pk = p0 + k * 12;
        v2f ak, bk, ck, dk;
        ak.x = pk[0]; ak.y = pk[4];
        bk.x = pk[1]; bk.y = pk[5];
        ck.x = pk[2]; ck.y = pk[6];
        dk.x = pk[3]; dk.y = pk[7];
        v2f nb = ak * b + bk;
        v2f nc = ck * a + cS;
        v2f nd = (dS + dk) + ck * b;
        a = ak * a; b = nb; cS = nc; dS = nd;
        O += pk[8];
    }
    float Rs  = ws[WS_BASE + row * 16 + 10];
    float U10 = -OCV0 - I0 * Rs;                 // U_H0 = 0
    float SH  = dS.x;                            // sum U_H/I
    float S1  = fmaf(cS.y, U10, dS.y);           // sum U_1/I
    out[row] = (O - SH - S1) * (1.0f / 4096.0f);
}

extern "C" void kernel_launch(void* const* d_in, const int* in_sizes, int n_in,
                              void* d_out, int out_size, void* d_ws, size_t ws_size,
                              hipStream_t stream) {
    const float* X   = (const float*)d_in[0];
    const float* SC  = (const float*)d_in[1];
    const float* pW1 = (const float*)d_in[2];
    const float* pb1 = (const float*)d_in[3];
    const float* pW2 = (const float*)d_in[4];
    const float* pb2 = (const float*)d_in[5];
    const float* rW1 = (const float*)d_in[6];
    const float* rb1 = (const float*)d_in[7];
    const float* rW2 = (const float*)d_in[8];
    const float* rb2 = (const float*)d_in[9];
    float* out = (float*)d_out;
    float* ws  = (float*)d_ws;

    onenet_prep<<<NB / 256, 256, 0, stream>>>(X, SC, pW1, pb1, pW2, pb2,
                                              rW1, rb1, rW2, rb2, ws);
    onenet_main<<<NB * 4, TPB, 0, stream>>>(X, ws);
    onenet_final<<<NB / 256, 256, 0, stream>>>(ws, out);
}